// Round 15
// baseline (605.816 us; speedup 1.0000x reference)
//
#include <hip/hip_runtime.h>
#include <math.h>

typedef unsigned short u16;
typedef __attribute__((ext_vector_type(4))) unsigned short u16x4;
typedef __attribute__((ext_vector_type(8))) short short8;
typedef __attribute__((ext_vector_type(4))) float f32x4;
typedef __attribute__((ext_vector_type(16))) float f32x16;

#define AS1 __attribute__((address_space(1)))
#define AS3 __attribute__((address_space(3)))

__device__ __forceinline__ void gload_lds16(const u16* g, u16* l) {
  __builtin_amdgcn_global_load_lds((AS1 void*)g, (AS3 void*)l, 16, 0, 0);
}

__device__ __forceinline__ float bf2f(u16 u) {
  union { unsigned i; float f; } c; c.i = ((unsigned)u) << 16; return c.f;
}
__device__ __forceinline__ u16 f2bf(float f) {
  union { float f; unsigned i; } c; c.f = f;
  unsigned r = c.i + 0x7fffu + ((c.i >> 16) & 1u);
  return (u16)(r >> 16);
}

// ---------------------------------------------------------------------------
// f32 -> bf16 bulk convert, 8 elems/thread, grid-stride.
// ---------------------------------------------------------------------------
__global__ __launch_bounds__(256)
void cvt_f32_bf16_k(const float* __restrict__ src, u16* __restrict__ dst, int n8)
{
  int i = blockIdx.x * blockDim.x + threadIdx.x;
  const int stride = gridDim.x * blockDim.x;
  for (; i < n8; i += stride) {
    float4 a = ((const float4*)src)[2 * i];
    float4 b = ((const float4*)src)[2 * i + 1];
    short8 o;
    o[0] = (short)f2bf(a.x); o[1] = (short)f2bf(a.y);
    o[2] = (short)f2bf(a.z); o[3] = (short)f2bf(a.w);
    o[4] = (short)f2bf(b.x); o[5] = (short)f2bf(b.y);
    o[6] = (short)f2bf(b.z); o[7] = (short)f2bf(b.w);
    ((short8*)dst)[i] = o;
  }
}

// ---------------------------------------------------------------------------
// Batched f32->bf16: hs (2M n8), wq (2M), wk (512K), wv (512K) in one launch.
// Kept to 4 tensors (218MB < L3) so hsb/wqb stay L3-resident for the QKV
// GEMM (r12 lesson: adding wo here evicted the GEMM inputs, +15us on GEMM).
// ---------------------------------------------------------------------------
__global__ __launch_bounds__(256)
void cvt_batch4(const float* __restrict__ s0, u16* __restrict__ d0,
                const float* __restrict__ s1, u16* __restrict__ d1,
                const float* __restrict__ s2, u16* __restrict__ d2,
                const float* __restrict__ s3, u16* __restrict__ d3)
{
  int i = blockIdx.x * blockDim.x + threadIdx.x;
  const int stride = gridDim.x * blockDim.x;
  for (; i < 5242880; i += stride) {
    const float* s; u16* d; int j;
    if (i < 2097152)      { s = s0; d = d0; j = i; }
    else if (i < 4194304) { s = s1; d = d1; j = i - 2097152; }
    else if (i < 4718592) { s = s2; d = d2; j = i - 4194304; }
    else                  { s = s3; d = d3; j = i - 4718592; }
    float4 a = ((const float4*)s)[2 * j];
    float4 b = ((const float4*)s)[2 * j + 1];
    short8 o;
    o[0] = (short)f2bf(a.x); o[1] = (short)f2bf(a.y);
    o[2] = (short)f2bf(a.z); o[3] = (short)f2bf(a.w);
    o[4] = (short)f2bf(b.x); o[5] = (short)f2bf(b.y);
    o[6] = (short)f2bf(b.z); o[7] = (short)f2bf(b.w);
    ((short8*)d)[j] = o;
  }
}

#define MFMA16(a, b, c) __builtin_amdgcn_mfma_f32_16x16x32_bf16((a), (b), (c), 0, 0, 0)

// ---------------------------------------------------------------------------
// 256x256 GEMM — r7/r13 schedule verbatim (best measured: 842 TF QKV; the
// r14 MFMA-reorder experiment cost +24 VGPR and -2% and is reverted), plus
// the r14 fused V-transpose epilogue (MODE 0, n0>=5120 -> Vt; neutral perf,
// removes the transpose_v kernel).
// ---------------------------------------------------------------------------
#define STAGE_H(panel, h, t, ldsb)                                          \
  { const u16* s_ = (panel) + (size_t)((h) * 128) * 4096 + (t) * 64;        \
    gload_lds16(s_,                   (ldsb) + ldst0);                      \
    gload_lds16(s_ + (size_t)64*4096, (ldsb) + 4096 + ldst0); }

#define PHASE(MB, STAGE_STMT, TAIL)                                         \
  {                                                                         \
    short8 a0k0 = *(const short8*)(aB + (MB)*1024 + aoff0);                 \
    short8 a0k1 = *(const short8*)(aB + (MB)*1024 + (aoff0 ^ 32));          \
    short8 a1k0 = *(const short8*)(aB + ((MB)+1)*1024 + aoff0);             \
    short8 a1k1 = *(const short8*)(aB + ((MB)+1)*1024 + (aoff0 ^ 32));      \
    STAGE_STMT                                                              \
    __builtin_amdgcn_s_barrier();                                           \
    asm volatile("s_waitcnt lgkmcnt(0)" ::: "memory");                      \
    __builtin_amdgcn_s_setprio(1);                                          \
    _Pragma("unroll")                                                       \
    for (int n = 0; n < 4; ++n) {                                           \
      acc[(MB)][n]   = MFMA16(a0k0, br[n][0], acc[(MB)][n]);                \
      acc[(MB)][n]   = MFMA16(a0k1, br[n][1], acc[(MB)][n]);                \
      acc[(MB)+1][n] = MFMA16(a1k0, br[n][0], acc[(MB)+1][n]);              \
      acc[(MB)+1][n] = MFMA16(a1k1, br[n][1], acc[(MB)+1][n]);              \
    }                                                                       \
    __builtin_amdgcn_s_setprio(0);                                          \
    TAIL                                                                    \
    __builtin_amdgcn_s_barrier();                                           \
  }

#define KTILE(BUF, T)                                                       \
  {                                                                         \
    const u16* aB = sA + (BUF) * 16384 + wr * 8192;                         \
    const u16* bB = sB + (BUF) * 16384 + (wc >> 1) * 8192;                  \
    u16* aO = sA + ((BUF) ^ 1) * 16384;                                     \
    u16* bO = sB + (BUF) * 16384;                                           \
    const bool st1 = (T) + 1 < NT, st2 = (T) + 2 < NT;                      \
    short8 br[4][2];                                                        \
    _Pragma("unroll")                                                       \
    for (int n = 0; n < 4; ++n) {                                           \
      br[n][0] = *(const short8*)(bB + n * 1024 + boff0);                   \
      br[n][1] = *(const short8*)(bB + n * 1024 + (boff0 ^ 32));            \
    }                                                                       \
    PHASE(0, if (st1) STAGE_H(aS, 0, (T) + 1, aO);, ;)                      \
    PHASE(2, if (st1) STAGE_H(aS, 1, (T) + 1, aO + 8192);, ;)               \
    PHASE(4, if (st2) STAGE_H(bS, 0, (T) + 2, bO);, ;)                      \
    PHASE(6, if (st2) STAGE_H(bS, 1, (T) + 2, bO + 8192);,                  \
          if ((T) < NT - 2) { asm volatile("s_waitcnt vmcnt(4)" ::: "memory"); } \
          else              { asm volatile("s_waitcnt vmcnt(0)" ::: "memory"); }) \
  }

template<int MODE, typename OutT>
__global__ __launch_bounds__(512, 2)
void gemm256(const u16* __restrict__ A, const u16* __restrict__ W0,
             const u16* __restrict__ W1, const u16* __restrict__ W2,
             OutT* __restrict__ C, u16* __restrict__ VT)
{
  constexpr int K = 4096;
  constexpr int NT = K / 64;
  constexpr int LDC = (MODE == 0) ? 6144 : 4096;
  constexpr int NBM = 16;
  constexpr int NBN = (MODE == 0) ? 24 : 16;
  constexpr int NWG = NBM * NBN;

  __shared__ __align__(16) u16 sA[2 * 16384];   // [buf][half][128][64]
  __shared__ __align__(16) u16 sB[2 * 16384];

  const int tid = threadIdx.x;
  const int wid = tid >> 6, lane = tid & 63;
  const int g = lane >> 4, li = lane & 15;
  const int wr = wid >> 2, wc = wid & 3;

  // XCD-aware bijective swizzle (NWG % 8 == 0)
  const int bid = blockIdx.x;
  const int wg = (bid & 7) * (NWG / 8) + (bid >> 3);
  const int bm = wg % NBM, bn = wg / NBM;
  const int n0 = bn * 256;

  const u16* Wp; int nrow0;
  if (MODE == 0) {
    if (n0 < 4096)      { Wp = W0; nrow0 = n0; }
    else if (n0 < 5120) { Wp = W1; nrow0 = n0 - 4096; }
    else                { Wp = W2; nrow0 = n0 - 5120; }
  } else { Wp = W0; nrow0 = n0; }

  const int r0 = tid >> 3;
  const int sc0 = (tid & 7) ^ (r0 & 7);
  const u16* aS = A  + (size_t)(bm * 256 + r0) * K + sc0 * 8;
  const u16* bS = Wp + (size_t)(nrow0   + r0) * K + sc0 * 8;
  const int ldst0 = wid * 512;            // wave-uniform LDS base (u16)

  const int aoff0 = li * 64 + ((g ^ (li & 7)) * 8);
  const int boff0 = (wc & 1) * 4096 + aoff0;

  f32x4 acc[8][4] = {};

  // prologue: buf0 = K-tile 0 (B0,B1,A0,A1), then buf1.B0,B1 = K-tile 1
  STAGE_H(bS, 0, 0, sB);
  STAGE_H(bS, 1, 0, sB + 8192);
  STAGE_H(aS, 0, 0, sA);
  STAGE_H(aS, 1, 0, sA + 8192);
  STAGE_H(bS, 0, 1, sB + 16384);
  STAGE_H(bS, 1, 1, sB + 24576);
  asm volatile("s_waitcnt vmcnt(4)" ::: "memory");
  __builtin_amdgcn_s_barrier();

  for (int t = 0; t < NT; t += 2) {
    KTILE(0, t)
    KTILE(1, t + 1)
  }

  if (MODE == 0 && n0 >= 5120) {
    // V panel: write transposed to Vt [B][8][128][T]; lane packs 4 t's.
#pragma unroll
    for (int m = 0; m < 8; ++m)
#pragma unroll
      for (int n = 0; n < 4; ++n) {
        int row0 = bm * 256 + wr * 128 + m * 16 + g * 4;
        int dcol = (n0 - 5120) + wc * 64 + n * 16 + li;   // 0..1023
        int bb = row0 >> 11, t0 = row0 & 2047;
        int hk = dcol >> 7, dd = dcol & 127;
        u16x4 pk;
#pragma unroll
        for (int j = 0; j < 4; ++j) pk[j] = f2bf(acc[m][n][j]);
        *(u16x4*)(VT + ((size_t)((bb * 8 + hk) * 128 + dd)) * 2048 + t0) = pk;
      }
  } else {
#pragma unroll
    for (int m = 0; m < 8; ++m)
#pragma unroll
      for (int n = 0; n < 4; ++n)
#pragma unroll
        for (int j = 0; j < 4; ++j) {
          int row = bm * 256 + wr * 128 + m * 16 + g * 4 + j;
          int col = n0 + wc * 64 + n * 16 + li;
          float v = acc[m][n][j];
          if constexpr (sizeof(OutT) == 2) C[(size_t)row * LDC + col] = (OutT)f2bf(v);
          else                             C[(size_t)row * LDC + col] = (OutT)v;
        }
  }
}

// ---------------------------------------------------------------------------
// Per-head RMSNorm + RoPE. One wave per head-row; lane l holds d=l and d=l+64.
// ---------------------------------------------------------------------------
__global__ __launch_bounds__(256)
void norm_rope(const u16* __restrict__ qkv, const float* __restrict__ qw,
               const float* __restrict__ kw, u16* __restrict__ Qo,
               u16* __restrict__ Ko)
{
  const int tid = threadIdx.x;
  const int wid = tid >> 6, l = tid & 63;
  const int idx = blockIdx.x * 4 + wid;

  const u16* src; const float* w; u16* dst; int t;
  if (idx < 131072) {                       // q rows: B*T*32
    int row = idx >> 5, h = idx & 31;
    int b = row >> 11; t = row & 2047;
    src = qkv + (size_t)row * 6144 + h * 128;
    w = qw;
    dst = Qo + (((size_t)(b * 32 + h)) * 2048 + t) * 128;
  } else {                                  // k rows: B*T*8
    int j = idx - 131072;
    int row = j >> 3, hk = j & 7;
    int b = row >> 11; t = row & 2047;
    src = qkv + (size_t)row * 6144 + 4096 + hk * 128;
    w = kw;
    dst = Ko + (((size_t)(b * 8 + hk)) * 2048 + t) * 128;
  }

  float x1 = bf2f(src[l]), x2 = bf2f(src[l + 64]);
  float ss = x1 * x1 + x2 * x2;
#pragma unroll
  for (int off = 32; off; off >>= 1) ss += __shfl_xor(ss, off);
  float rn = rsqrtf(ss * (1.0f / 128.0f) + 1e-6f);
  float y1 = x1 * rn * w[l];
  float y2 = x2 * rn * w[l + 64];

  float ang = (float)t * expf((float)l * -0.21586735246819178f);
  float c = cosf(ang), s = sinf(ang);
  dst[l]      = f2bf(y1 * c - y2 * s);
  dst[l + 64] = f2bf(y2 * c + y1 * s);
}

// ---------------------------------------------------------------------------
// Causal flash attention — m214-style 32x32 structure (r5, best measured).
// ---------------------------------------------------------------------------
__global__ __launch_bounds__(256, 2)
void attn_fwd(const u16* __restrict__ Q, const u16* __restrict__ Kc,
              const u16* __restrict__ Vt, u16* __restrict__ O)
{
  const int qt = 15 - (int)blockIdx.x;   // heavy blocks first
  const int bh = blockIdx.y;
  const int b = bh >> 5, h = bh & 31, hkv = h >> 2;
  const int tid = threadIdx.x, wid = tid >> 6;
  const int lane = tid & 63, ql = lane & 31, hi = lane >> 5;

  __shared__ __align__(16) u16 sK[2][64 * 128];
  __shared__ __align__(16) u16 sV[2][128 * 64];

  const u16* Kb = Kc + ((size_t)(b * 8 + hkv)) * 2048 * 128;
  const u16* Vb = Vt + ((size_t)(b * 8 + hkv)) * 128 * 2048;

  const int kr0 = tid >> 4;
  const u16* kSrc = Kb + (size_t)kr0 * 128 + (((tid & 15) ^ (kr0 & 7)) * 8);
  const int vr0 = tid >> 3;
  const u16* vSrc = Vb + (size_t)vr0 * 2048 + (((tid & 7) ^ (vr0 & 7)) * 8);
  u16* const kDst = (u16*)sK[0] + wid * 512;
  u16* const vDst = (u16*)sV[0] + wid * 512;

  const int qg = qt * 128 + wid * 32 + ql;
  const u16* qrow = Q + ((size_t)(b * 32 + h) * 2048 + qg) * 128;
  short8 qf[8];
#pragma unroll
  for (int m = 0; m < 8; ++m) qf[m] = *(const short8*)(qrow + m * 16 + hi * 8);

  f32x16 oacc[4] = {};
  float mrun = -INFINITY, lrun = 0.f;
  const float scale = 0.08838834764831845f;
  const int nt = 2 * qt + 2;

#pragma unroll
  for (int p = 0; p < 4; ++p) {
    gload_lds16(kSrc + p * 2048,  kDst + p * 2048);
    gload_lds16(vSrc + p * 65536, vDst + p * 2048);
  }
  asm volatile("s_waitcnt vmcnt(0)" ::: "memory");
  __builtin_amdgcn_s_barrier();

  int cur = 0;
  for (int kt = 0; kt < nt; ++kt) {
    const int kv0 = kt * 64;
    if (kt + 1 < nt) {
      const u16* ks = kSrc + (size_t)(kv0 + 64) * 128;
      const u16* vs = vSrc + (kv0 + 64);
      u16* kd = kDst + (cur ^ 1) * 8192;
      u16* vd = vDst + (cur ^ 1) * 8192;
#pragma unroll
      for (int p = 0; p < 4; ++p) {
        gload_lds16(ks + p * 2048,  kd + p * 2048);
        gload_lds16(vs + p * 65536, vd + p * 2048);
      }
    }
    const u16* sKc = sK[cur];
    const u16* sVc = sV[cur];

    f32x16 P0 = {}, P1 = {};
    __builtin_amdgcn_s_setprio(1);
#pragma unroll
    for (int m = 0; m < 8; ++m) {
      const int c0 = ((m * 2 + hi) ^ (ql & 7)) * 8;
      short8 k0 = *(const short8*)(sKc + ql * 128 + c0);
      short8 k1 = *(const short8*)(sKc + (32 + ql) * 128 + c0);
      P0 = __builtin_amdgcn_mfma_f32_32x32x16_bf16(k0, qf[m], P0, 0, 0, 0);
      P1 = __builtin_amdgcn_mfma_f32_32x32x16_bf16(k1, qf[m], P1, 0, 0, 0);
    }
    __builtin_amdgcn_s_setprio(0);

#pragma unroll
    for (int r = 0; r < 16; ++r) {
      const int kvl = (r & 3) + 8 * (r >> 2) + 4 * hi;
      float v0 = P0[r] * scale; if (kv0 + kvl > qg)      v0 = -INFINITY; P0[r] = v0;
      float v1 = P1[r] * scale; if (kv0 + 32 + kvl > qg) v1 = -INFINITY; P1[r] = v1;
    }

    float pmax = -INFINITY;
#pragma unroll
    for (int r = 0; r < 16; ++r) pmax = fmaxf(pmax, fmaxf(P0[r], P1[r]));
    pmax = fmaxf(pmax, __shfl_xor(pmax, 32));

    if (!__all(pmax - mrun <= 8.f)) {
      float mnew = fmaxf(mrun, pmax);
      float corr = __expf(mrun - mnew);
      lrun *= corr;
      mrun = mnew;
#pragma unroll
      for (int r = 0; r < 16; ++r) {
        int qidx = (r & 3) + 8 * (r >> 2) + 4 * hi;
        float cr = __shfl(corr, qidx);
#pragma unroll
        for (int dt = 0; dt < 4; ++dt) oacc[dt][r] *= cr;
      }
    }

    float psum = 0.f;
#pragma unroll
    for (int r = 0; r < 16; ++r) {
      float e0 = __expf(P0[r] - mrun); P0[r] = e0; psum += e0;
      float e1 = __expf(P1[r] - mrun); P1[r] = e1; psum += e1;
    }
    psum += __shfl_xor(psum, 32);
    lrun += psum;

    __builtin_amdgcn_s_setprio(1);
#pragma unroll
    for (int s = 0; s < 4; ++s) {
      const int R0 = 8 * (s & 1), R1 = R0 + 4;
      float a0 = (s < 2) ? P0[R0 + 0] : P1[R0 + 0];
      float a1 = (s < 2) ? P0[R0 + 1] : P1[R0 + 1];
      float a2 = (s < 2) ? P0[R0 + 2] : P1[R0 + 2];
      float a3 = (s < 2) ? P0[R0 + 3] : P1[R0 + 3];
      float b0 = (s < 2) ? P0[R1 + 0] : P1[R1 + 0];
      float b1 = (s < 2) ? P0[R1 + 1] : P1[R1 + 1];
      float b2 = (s < 2) ? P0[R1 + 2] : P1[R1 + 2];
      float b3 = (s < 2) ? P0[R1 + 3] : P1[R1 + 3];
      unsigned y0, y1, z0, z1;
      asm("v_cvt_pk_bf16_f32 %0, %1, %2" : "=v"(y0) : "v"(a0), "v"(a1));
      asm("v_cvt_pk_bf16_f32 %0, %1, %2" : "=v"(z0) : "v"(b0), "v"(b1));
      asm("v_cvt_pk_bf16_f32 %0, %1, %2" : "=v"(y1) : "v"(a2), "v"(a3));
      asm("v_cvt_pk_bf16_f32 %0, %1, %2" : "=v"(z1) : "v"(b2), "v"(b3));
      asm("v_permlane32_swap_b32 %0, %1" : "+v"(y0), "+v"(z0));
      asm("v_permlane32_swap_b32 %0, %1" : "+v"(y1), "+v"(z1));
      union { unsigned u[4]; short8 v; } pa;
      pa.u[0] = y0; pa.u[1] = y1; pa.u[2] = z0; pa.u[3] = z1;
#pragma unroll
      for (int dt = 0; dt < 4; ++dt) {
        const int c = ((s * 2 + hi) ^ (ql & 7)) * 8;
        short8 vf = *(const short8*)(sVc + (dt * 32 + ql) * 64 + c);
        oacc[dt] = __builtin_amdgcn_mfma_f32_32x32x16_bf16(pa.v, vf, oacc[dt], 0, 0, 0);
      }
    }
    __builtin_amdgcn_s_setprio(0);

    asm volatile("s_waitcnt lgkmcnt(0)" ::: "memory");
    asm volatile("s_waitcnt vmcnt(0)" ::: "memory");
    __builtin_amdgcn_s_barrier();
    cur ^= 1;
  }

  float inv = 1.f / lrun;
  const int qbase = b * 2048 + qt * 128 + wid * 32;
#pragma unroll
  for (int r = 0; r < 16; ++r) {
    const int qidx = (r & 3) + 8 * (r >> 2) + 4 * hi;
    float ir = __shfl(inv, qidx);
    size_t base = (size_t)(qbase + qidx) * 4096 + h * 128 + ql;
#pragma unroll
    for (int dt = 0; dt < 4; ++dt)
      O[base + dt * 32] = f2bf(oacc[dt][r] * ir);
  }
}

// ---------------------------------------------------------------------------
extern "C" void kernel_launch(void* const* d_in, const int* in_sizes, int n_in,
                              void* d_out, int out_size, void* d_ws, size_t ws_size,
                              hipStream_t stream) {
  const float* hs  = (const float*)d_in[0];
  const float* wq  = (const float*)d_in[1];
  const float* wk  = (const float*)d_in[2];
  const float* wv  = (const float*)d_in[3];
  const float* wo  = (const float*)d_in[4];
  const float* qnw = (const float*)d_in[5];
  const float* knw = (const float*)d_in[6];
  float* out = (float*)d_out;

  char* ws = (char*)d_ws;
  u16* qkv = (u16*)(ws);                  // [4096][6144] bf16   50.33 MB
  u16* qr  = (u16*)(ws + 50331648);       // [2][32][2048][128]  33.55 MB
  u16* kr  = (u16*)(ws + 83886080);       // [2][8][2048][128]    8.39 MB
  u16* vt  = (u16*)(ws + 92274688);       // [2][8][128][2048]    8.39 MB
  u16* hsb = (u16*)(ws + 100663296);      // hs bf16             33.55 MB
  u16* wqb = (u16*)(ws + 134217728);      // wq bf16             33.55 MB
  u16* wkb = (u16*)(ws + 167772160);      // wk bf16              8.39 MB
  u16* wvb = (u16*)(ws + 176160768);      // wv bf16              8.39 MB
  u16* ao  = (u16*)(ws);                  // attn out reuses dead qkv region
  u16* wob = hsb;                         // wo bf16 reuses hsb (dead post-QKV)

  cvt_batch4<<<dim3(2048), dim3(256), 0, stream>>>(hs, hsb, wq, wqb, wk, wkb, wv, wvb);

  gemm256<0, u16><<<dim3(384), dim3(512), 0, stream>>>(hsb, wqb, wkb, wvb, qkv, vt);
  norm_rope<<<dim3(40960), dim3(256), 0, stream>>>(qkv, qnw, knw, qr, kr);
  attn_fwd<<<dim3(16, 64), dim3(256), 0, stream>>>(qr, kr, vt, ao);

  cvt_f32_bf16_k<<<dim3(2048), dim3(256), 0, stream>>>(wo, wob, 16777216 / 8);
  gemm256<1, float><<<dim3(256), dim3(512), 0, stream>>>(ao, wob, nullptr, nullptr, out, nullptr);
}

// Round 16
// 604.826 us; speedup vs baseline: 1.0016x; 1.0016x over previous
//
#include <hip/hip_runtime.h>
#include <math.h>

typedef unsigned short u16;
typedef __attribute__((ext_vector_type(8))) short short8;
typedef __attribute__((ext_vector_type(4))) float f32x4;
typedef __attribute__((ext_vector_type(16))) float f32x16;

#define AS1 __attribute__((address_space(1)))
#define AS3 __attribute__((address_space(3)))

__device__ __forceinline__ void gload_lds16(const u16* g, u16* l) {
  __builtin_amdgcn_global_load_lds((AS1 void*)g, (AS3 void*)l, 16, 0, 0);
}

__device__ __forceinline__ float bf2f(u16 u) {
  union { unsigned i; float f; } c; c.i = ((unsigned)u) << 16; return c.f;
}
__device__ __forceinline__ u16 f2bf(float f) {
  union { float f; unsigned i; } c; c.f = f;
  unsigned r = c.i + 0x7fffu + ((c.i >> 16) & 1u);
  return (u16)(r >> 16);
}

// ---------------------------------------------------------------------------
// f32 -> bf16 bulk convert, 8 elems/thread, grid-stride.
// ---------------------------------------------------------------------------
__global__ __launch_bounds__(256)
void cvt_f32_bf16_k(const float* __restrict__ src, u16* __restrict__ dst, int n8)
{
  int i = blockIdx.x * blockDim.x + threadIdx.x;
  const int stride = gridDim.x * blockDim.x;
  for (; i < n8; i += stride) {
    float4 a = ((const float4*)src)[2 * i];
    float4 b = ((const float4*)src)[2 * i + 1];
    short8 o;
    o[0] = (short)f2bf(a.x); o[1] = (short)f2bf(a.y);
    o[2] = (short)f2bf(a.z); o[3] = (short)f2bf(a.w);
    o[4] = (short)f2bf(b.x); o[5] = (short)f2bf(b.y);
    o[6] = (short)f2bf(b.z); o[7] = (short)f2bf(b.w);
    ((short8*)dst)[i] = o;
  }
}

// ---------------------------------------------------------------------------
// Batched f32->bf16: hs (2M n8), wq (2M), wk (512K), wv (512K) in one launch.
// Kept to 4 tensors (218MB < L3) so hsb/wqb stay L3-resident for the QKV
// GEMM (r12 lesson: adding wo here evicted the GEMM inputs, +15us on GEMM).
// ---------------------------------------------------------------------------
__global__ __launch_bounds__(256)
void cvt_batch4(const float* __restrict__ s0, u16* __restrict__ d0,
                const float* __restrict__ s1, u16* __restrict__ d1,
                const float* __restrict__ s2, u16* __restrict__ d2,
                const float* __restrict__ s3, u16* __restrict__ d3)
{
  int i = blockIdx.x * blockDim.x + threadIdx.x;
  const int stride = gridDim.x * blockDim.x;
  for (; i < 5242880; i += stride) {
    const float* s; u16* d; int j;
    if (i < 2097152)      { s = s0; d = d0; j = i; }
    else if (i < 4194304) { s = s1; d = d1; j = i - 2097152; }
    else if (i < 4718592) { s = s2; d = d2; j = i - 4194304; }
    else                  { s = s3; d = d3; j = i - 4718592; }
    float4 a = ((const float4*)s)[2 * j];
    float4 b = ((const float4*)s)[2 * j + 1];
    short8 o;
    o[0] = (short)f2bf(a.x); o[1] = (short)f2bf(a.y);
    o[2] = (short)f2bf(a.z); o[3] = (short)f2bf(a.w);
    o[4] = (short)f2bf(b.x); o[5] = (short)f2bf(b.y);
    o[6] = (short)f2bf(b.z); o[7] = (short)f2bf(b.w);
    ((short8*)d)[j] = o;
  }
}

#define MFMA16(a, b, c) __builtin_amdgcn_mfma_f32_16x16x32_bf16((a), (b), (c), 0, 0, 0)

// ---------------------------------------------------------------------------
// 256x256 GEMM — r7/r13 configuration verbatim (best measured: 842 TF QKV).
// BK=64, 512 thr = 8 waves (2M x 4N), per-wave 128x64 out (acc[8][4]).
// LDS 128KB, 16B-unit XOR swizzle (unit ^= row&7) pre-applied on global src,
// de-swizzled on ds_read. Per K-tile: 4 phases {ds_read | stage half-tile |
// BAR | lgkm0 | 16 MFMA | TAIL | BAR}; stage p0/p1 = A(t+1)->buf^1,
// p2/p3 = B(t+2)->buf; one vmcnt(4) per K-tile (vmcnt(0) last two).
// ---------------------------------------------------------------------------
#define STAGE_H(panel, h, t, ldsb)                                          \
  { const u16* s_ = (panel) + (size_t)((h) * 128) * 4096 + (t) * 64;        \
    gload_lds16(s_,                   (ldsb) + ldst0);                      \
    gload_lds16(s_ + (size_t)64*4096, (ldsb) + 4096 + ldst0); }

#define PHASE(MB, STAGE_STMT, TAIL)                                         \
  {                                                                         \
    short8 a0k0 = *(const short8*)(aB + (MB)*1024 + aoff0);                 \
    short8 a0k1 = *(const short8*)(aB + (MB)*1024 + (aoff0 ^ 32));          \
    short8 a1k0 = *(const short8*)(aB + ((MB)+1)*1024 + aoff0);             \
    short8 a1k1 = *(const short8*)(aB + ((MB)+1)*1024 + (aoff0 ^ 32));      \
    STAGE_STMT                                                              \
    __builtin_amdgcn_s_barrier();                                           \
    asm volatile("s_waitcnt lgkmcnt(0)" ::: "memory");                      \
    __builtin_amdgcn_s_setprio(1);                                          \
    _Pragma("unroll")                                                       \
    for (int n = 0; n < 4; ++n) {                                           \
      acc[(MB)][n]   = MFMA16(a0k0, br[n][0], acc[(MB)][n]);                \
      acc[(MB)][n]   = MFMA16(a0k1, br[n][1], acc[(MB)][n]);                \
      acc[(MB)+1][n] = MFMA16(a1k0, br[n][0], acc[(MB)+1][n]);              \
      acc[(MB)+1][n] = MFMA16(a1k1, br[n][1], acc[(MB)+1][n]);              \
    }                                                                       \
    __builtin_amdgcn_s_setprio(0);                                          \
    TAIL                                                                    \
    __builtin_amdgcn_s_barrier();                                           \
  }

#define KTILE(BUF, T)                                                       \
  {                                                                         \
    const u16* aB = sA + (BUF) * 16384 + wr * 8192;                         \
    const u16* bB = sB + (BUF) * 16384 + (wc >> 1) * 8192;                  \
    u16* aO = sA + ((BUF) ^ 1) * 16384;                                     \
    u16* bO = sB + (BUF) * 16384;                                           \
    const bool st1 = (T) + 1 < NT, st2 = (T) + 2 < NT;                      \
    short8 br[4][2];                                                        \
    _Pragma("unroll")                                                       \
    for (int n = 0; n < 4; ++n) {                                           \
      br[n][0] = *(const short8*)(bB + n * 1024 + boff0);                   \
      br[n][1] = *(const short8*)(bB + n * 1024 + (boff0 ^ 32));            \
    }                                                                       \
    PHASE(0, if (st1) STAGE_H(aS, 0, (T) + 1, aO);, ;)                      \
    PHASE(2, if (st1) STAGE_H(aS, 1, (T) + 1, aO + 8192);, ;)               \
    PHASE(4, if (st2) STAGE_H(bS, 0, (T) + 2, bO);, ;)                      \
    PHASE(6, if (st2) STAGE_H(bS, 1, (T) + 2, bO + 8192);,                  \
          if ((T) < NT - 2) { asm volatile("s_waitcnt vmcnt(4)" ::: "memory"); } \
          else              { asm volatile("s_waitcnt vmcnt(0)" ::: "memory"); }) \
  }

template<int MODE, typename OutT>
__global__ __launch_bounds__(512, 2)
void gemm256(const u16* __restrict__ A, const u16* __restrict__ W0,
             const u16* __restrict__ W1, const u16* __restrict__ W2,
             OutT* __restrict__ C)
{
  constexpr int K = 4096;
  constexpr int NT = K / 64;
  constexpr int LDC = (MODE == 0) ? 6144 : 4096;
  constexpr int NBM = 16;
  constexpr int NBN = (MODE == 0) ? 24 : 16;
  constexpr int NWG = NBM * NBN;

  __shared__ __align__(16) u16 sA[2 * 16384];   // [buf][half][128][64]
  __shared__ __align__(16) u16 sB[2 * 16384];

  const int tid = threadIdx.x;
  const int wid = tid >> 6, lane = tid & 63;
  const int g = lane >> 4, li = lane & 15;
  const int wr = wid >> 2, wc = wid & 3;

  // XCD-aware bijective swizzle (NWG % 8 == 0)
  const int bid = blockIdx.x;
  const int wg = (bid & 7) * (NWG / 8) + (bid >> 3);
  const int bm = wg % NBM, bn = wg / NBM;
  const int n0 = bn * 256;

  const u16* Wp; int nrow0;
  if (MODE == 0) {
    if (n0 < 4096)      { Wp = W0; nrow0 = n0; }
    else if (n0 < 5120) { Wp = W1; nrow0 = n0 - 4096; }
    else                { Wp = W2; nrow0 = n0 - 5120; }
  } else { Wp = W0; nrow0 = n0; }

  const int r0 = tid >> 3;
  const int sc0 = (tid & 7) ^ (r0 & 7);
  const u16* aS = A  + (size_t)(bm * 256 + r0) * K + sc0 * 8;
  const u16* bS = Wp + (size_t)(nrow0   + r0) * K + sc0 * 8;
  const int ldst0 = wid * 512;            // wave-uniform LDS base (u16)

  const int aoff0 = li * 64 + ((g ^ (li & 7)) * 8);
  const int boff0 = (wc & 1) * 4096 + aoff0;

  f32x4 acc[8][4] = {};

  // prologue: buf0 = K-tile 0 (B0,B1,A0,A1), then buf1.B0,B1 = K-tile 1
  STAGE_H(bS, 0, 0, sB);
  STAGE_H(bS, 1, 0, sB + 8192);
  STAGE_H(aS, 0, 0, sA);
  STAGE_H(aS, 1, 0, sA + 8192);
  STAGE_H(bS, 0, 1, sB + 16384);
  STAGE_H(bS, 1, 1, sB + 24576);
  asm volatile("s_waitcnt vmcnt(4)" ::: "memory");
  __builtin_amdgcn_s_barrier();

  for (int t = 0; t < NT; t += 2) {
    KTILE(0, t)
    KTILE(1, t + 1)
  }

#pragma unroll
  for (int m = 0; m < 8; ++m)
#pragma unroll
    for (int n = 0; n < 4; ++n)
#pragma unroll
      for (int j = 0; j < 4; ++j) {
        int row = bm * 256 + wr * 128 + m * 16 + g * 4 + j;
        int col = n0 + wc * 64 + n * 16 + li;
        float v = acc[m][n][j];
        if constexpr (sizeof(OutT) == 2) C[(size_t)row * LDC + col] = (OutT)f2bf(v);
        else                             C[(size_t)row * LDC + col] = (OutT)v;
      }
}

// ---------------------------------------------------------------------------
// Per-head RMSNorm + RoPE. One wave per head-row; lane l holds d=l and d=l+64.
// ---------------------------------------------------------------------------
__global__ __launch_bounds__(256)
void norm_rope(const u16* __restrict__ qkv, const float* __restrict__ qw,
               const float* __restrict__ kw, u16* __restrict__ Qo,
               u16* __restrict__ Ko)
{
  const int tid = threadIdx.x;
  const int wid = tid >> 6, l = tid & 63;
  const int idx = blockIdx.x * 4 + wid;

  const u16* src; const float* w; u16* dst; int t;
  if (idx < 131072) {                       // q rows: B*T*32
    int row = idx >> 5, h = idx & 31;
    int b = row >> 11; t = row & 2047;
    src = qkv + (size_t)row * 6144 + h * 128;
    w = qw;
    dst = Qo + (((size_t)(b * 32 + h)) * 2048 + t) * 128;
  } else {                                  // k rows: B*T*8
    int j = idx - 131072;
    int row = j >> 3, hk = j & 7;
    int b = row >> 11; t = row & 2047;
    src = qkv + (size_t)row * 6144 + 4096 + hk * 128;
    w = kw;
    dst = Ko + (((size_t)(b * 8 + hk)) * 2048 + t) * 128;
  }

  float x1 = bf2f(src[l]), x2 = bf2f(src[l + 64]);
  float ss = x1 * x1 + x2 * x2;
#pragma unroll
  for (int off = 32; off; off >>= 1) ss += __shfl_xor(ss, off);
  float rn = rsqrtf(ss * (1.0f / 128.0f) + 1e-6f);
  float y1 = x1 * rn * w[l];
  float y2 = x2 * rn * w[l + 64];

  float ang = (float)t * expf((float)l * -0.21586735246819178f);
  float c = cosf(ang), s = sinf(ang);
  dst[l]      = f2bf(y1 * c - y2 * s);
  dst[l + 64] = f2bf(y2 * c + y1 * s);
}

// ---------------------------------------------------------------------------
// V transpose: qkv V-cols [B*T][5120+hkv*128+d] -> Vt [B][8][128][T]
// ---------------------------------------------------------------------------
__global__ __launch_bounds__(256)
void transpose_v(const u16* __restrict__ qkv, u16* __restrict__ Vt)
{
  const int tblk = blockIdx.x, bh = blockIdx.y;
  const int b = bh >> 3, hk = bh & 7;
  const int tid = threadIdx.x;
  __shared__ __align__(16) u16 tile[64][136];

#pragma unroll
  for (int r = 0; r < 4; ++r) {
    int u = tid + r * 256;
    int row = u >> 4, cu = u & 15;
    short8 v = *(const short8*)(qkv + (size_t)(b * 2048 + tblk * 64 + row) * 6144
                                + 5120 + hk * 128 + cu * 8);
    *(short8*)(&tile[row][cu * 8]) = v;
  }
  __syncthreads();
#pragma unroll
  for (int it = 0; it < 4; ++it) {
    int u = tid + it * 256;
    int d = u & 127, tg = u >> 7;
    short8 wv8;
#pragma unroll
    for (int j = 0; j < 8; ++j) wv8[j] = (short)tile[tg * 8 + j][d];
    *(short8*)(Vt + ((size_t)(b * 8 + hk) * 128 + d) * 2048 + tblk * 64 + tg * 8) = wv8;
  }
}

// ---------------------------------------------------------------------------
// Causal flash attention — m214-style 32x32 structure (r5, best measured).
// ---------------------------------------------------------------------------
__global__ __launch_bounds__(256, 2)
void attn_fwd(const u16* __restrict__ Q, const u16* __restrict__ Kc,
              const u16* __restrict__ Vt, u16* __restrict__ O)
{
  const int qt = 15 - (int)blockIdx.x;   // heavy blocks first
  const int bh = blockIdx.y;
  const int b = bh >> 5, h = bh & 31, hkv = h >> 2;
  const int tid = threadIdx.x, wid = tid >> 6;
  const int lane = tid & 63, ql = lane & 31, hi = lane >> 5;

  __shared__ __align__(16) u16 sK[2][64 * 128];
  __shared__ __align__(16) u16 sV[2][128 * 64];

  const u16* Kb = Kc + ((size_t)(b * 8 + hkv)) * 2048 * 128;
  const u16* Vb = Vt + ((size_t)(b * 8 + hkv)) * 128 * 2048;

  const int kr0 = tid >> 4;
  const u16* kSrc = Kb + (size_t)kr0 * 128 + (((tid & 15) ^ (kr0 & 7)) * 8);
  const int vr0 = tid >> 3;
  const u16* vSrc = Vb + (size_t)vr0 * 2048 + (((tid & 7) ^ (vr0 & 7)) * 8);
  u16* const kDst = (u16*)sK[0] + wid * 512;
  u16* const vDst = (u16*)sV[0] + wid * 512;

  const int qg = qt * 128 + wid * 32 + ql;
  const u16* qrow = Q + ((size_t)(b * 32 + h) * 2048 + qg) * 128;
  short8 qf[8];
#pragma unroll
  for (int m = 0; m < 8; ++m) qf[m] = *(const short8*)(qrow + m * 16 + hi * 8);

  f32x16 oacc[4] = {};
  float mrun = -INFINITY, lrun = 0.f;
  const float scale = 0.08838834764831845f;
  const int nt = 2 * qt + 2;

#pragma unroll
  for (int p = 0; p < 4; ++p) {
    gload_lds16(kSrc + p * 2048,  kDst + p * 2048);
    gload_lds16(vSrc + p * 65536, vDst + p * 2048);
  }
  asm volatile("s_waitcnt vmcnt(0)" ::: "memory");
  __builtin_amdgcn_s_barrier();

  int cur = 0;
  for (int kt = 0; kt < nt; ++kt) {
    const int kv0 = kt * 64;
    if (kt + 1 < nt) {
      const u16* ks = kSrc + (size_t)(kv0 + 64) * 128;
      const u16* vs = vSrc + (kv0 + 64);
      u16* kd = kDst + (cur ^ 1) * 8192;
      u16* vd = vDst + (cur ^ 1) * 8192;
#pragma unroll
      for (int p = 0; p < 4; ++p) {
        gload_lds16(ks + p * 2048,  kd + p * 2048);
        gload_lds16(vs + p * 65536, vd + p * 2048);
      }
    }
    const u16* sKc = sK[cur];
    const u16* sVc = sV[cur];

    f32x16 P0 = {}, P1 = {};
    __builtin_amdgcn_s_setprio(1);
#pragma unroll
    for (int m = 0; m < 8; ++m) {
      const int c0 = ((m * 2 + hi) ^ (ql & 7)) * 8;
      short8 k0 = *(const short8*)(sKc + ql * 128 + c0);
      short8 k1 = *(const short8*)(sKc + (32 + ql) * 128 + c0);
      P0 = __builtin_amdgcn_mfma_f32_32x32x16_bf16(k0, qf[m], P0, 0, 0, 0);
      P1 = __builtin_amdgcn_mfma_f32_32x32x16_bf16(k1, qf[m], P1, 0, 0, 0);
    }
    __builtin_amdgcn_s_setprio(0);

#pragma unroll
    for (int r = 0; r < 16; ++r) {
      const int kvl = (r & 3) + 8 * (r >> 2) + 4 * hi;
      float v0 = P0[r] * scale; if (kv0 + kvl > qg)      v0 = -INFINITY; P0[r] = v0;
      float v1 = P1[r] * scale; if (kv0 + 32 + kvl > qg) v1 = -INFINITY; P1[r] = v1;
    }

    float pmax = -INFINITY;
#pragma unroll
    for (int r = 0; r < 16; ++r) pmax = fmaxf(pmax, fmaxf(P0[r], P1[r]));
    pmax = fmaxf(pmax, __shfl_xor(pmax, 32));

    if (!__all(pmax - mrun <= 8.f)) {
      float mnew = fmaxf(mrun, pmax);
      float corr = __expf(mrun - mnew);
      lrun *= corr;
      mrun = mnew;
#pragma unroll
      for (int r = 0; r < 16; ++r) {
        int qidx = (r & 3) + 8 * (r >> 2) + 4 * hi;
        float cr = __shfl(corr, qidx);
#pragma unroll
        for (int dt = 0; dt < 4; ++dt) oacc[dt][r] *= cr;
      }
    }

    float psum = 0.f;
#pragma unroll
    for (int r = 0; r < 16; ++r) {
      float e0 = __expf(P0[r] - mrun); P0[r] = e0; psum += e0;
      float e1 = __expf(P1[r] - mrun); P1[r] = e1; psum += e1;
    }
    psum += __shfl_xor(psum, 32);
    lrun += psum;

    __builtin_amdgcn_s_setprio(1);
#pragma unroll
    for (int s = 0; s < 4; ++s) {
      const int R0 = 8 * (s & 1), R1 = R0 + 4;
      float a0 = (s < 2) ? P0[R0 + 0] : P1[R0 + 0];
      float a1 = (s < 2) ? P0[R0 + 1] : P1[R0 + 1];
      float a2 = (s < 2) ? P0[R0 + 2] : P1[R0 + 2];
      float a3 = (s < 2) ? P0[R0 + 3] : P1[R0 + 3];
      float b0 = (s < 2) ? P0[R1 + 0] : P1[R1 + 0];
      float b1 = (s < 2) ? P0[R1 + 1] : P1[R1 + 1];
      float b2 = (s < 2) ? P0[R1 + 2] : P1[R1 + 2];
      float b3 = (s < 2) ? P0[R1 + 3] : P1[R1 + 3];
      unsigned y0, y1, z0, z1;
      asm("v_cvt_pk_bf16_f32 %0, %1, %2" : "=v"(y0) : "v"(a0), "v"(a1));
      asm("v_cvt_pk_bf16_f32 %0, %1, %2" : "=v"(z0) : "v"(b0), "v"(b1));
      asm("v_cvt_pk_bf16_f32 %0, %1, %2" : "=v"(y1) : "v"(a2), "v"(a3));
      asm("v_cvt_pk_bf16_f32 %0, %1, %2" : "=v"(z1) : "v"(b2), "v"(b3));
      asm("v_permlane32_swap_b32 %0, %1" : "+v"(y0), "+v"(z0));
      asm("v_permlane32_swap_b32 %0, %1" : "+v"(y1), "+v"(z1));
      union { unsigned u[4]; short8 v; } pa;
      pa.u[0] = y0; pa.u[1] = y1; pa.u[2] = z0; pa.u[3] = z1;
#pragma unroll
      for (int dt = 0; dt < 4; ++dt) {
        const int c = ((s * 2 + hi) ^ (ql & 7)) * 8;
        short8 vf = *(const short8*)(sVc + (dt * 32 + ql) * 64 + c);
        oacc[dt] = __builtin_amdgcn_mfma_f32_32x32x16_bf16(pa.v, vf, oacc[dt], 0, 0, 0);
      }
    }
    __builtin_amdgcn_s_setprio(0);

    asm volatile("s_waitcnt lgkmcnt(0)" ::: "memory");
    asm volatile("s_waitcnt vmcnt(0)" ::: "memory");
    __builtin_amdgcn_s_barrier();
    cur ^= 1;
  }

  float inv = 1.f / lrun;
  const int qbase = b * 2048 + qt * 128 + wid * 32;
#pragma unroll
  for (int r = 0; r < 16; ++r) {
    const int qidx = (r & 3) + 8 * (r >> 2) + 4 * hi;
    float ir = __shfl(inv, qidx);
    size_t base = (size_t)(qbase + qidx) * 4096 + h * 128 + ql;
#pragma unroll
    for (int dt = 0; dt < 4; ++dt)
      O[base + dt * 32] = f2bf(oacc[dt][r] * ir);
  }
}

// ---------------------------------------------------------------------------
extern "C" void kernel_launch(void* const* d_in, const int* in_sizes, int n_in,
                              void* d_out, int out_size, void* d_ws, size_t ws_size,
                              hipStream_t stream) {
  const float* hs  = (const float*)d_in[0];
  const float* wq  = (const float*)d_in[1];
  const float* wk  = (const float*)d_in[2];
  const float* wv  = (const float*)d_in[3];
  const float* wo  = (const float*)d_in[4];
  const float* qnw = (const float*)d_in[5];
  const float* knw = (const float*)d_in[6];
  float* out = (float*)d_out;

  char* ws = (char*)d_ws;
  u16* qkv = (u16*)(ws);                  // [4096][6144] bf16   50.33 MB
  u16* qr  = (u16*)(ws + 50331648);       // [2][32][2048][128]  33.55 MB
  u16* kr  = (u16*)(ws + 83886080);       // [2][8][2048][128]    8.39 MB
  u16* vt  = (u16*)(ws + 92274688);       // [2][8][128][2048]    8.39 MB
  u16* hsb = (u16*)(ws + 100663296);      // hs bf16             33.55 MB
  u16* wqb = (u16*)(ws + 134217728);      // wq bf16             33.55 MB
  u16* wkb = (u16*)(ws + 167772160);      // wk bf16              8.39 MB
  u16* wvb = (u16*)(ws + 176160768);      // wv bf16              8.39 MB
  u16* ao  = (u16*)(ws);                  // attn out reuses dead qkv region
  u16* wob = hsb;                         // wo bf16 reuses hsb (dead post-QKV)

  cvt_batch4<<<dim3(2048), dim3(256), 0, stream>>>(hs, hsb, wq, wqb, wk, wkb, wv, wvb);

  gemm256<0, u16><<<dim3(384), dim3(512), 0, stream>>>(hsb, wqb, wkb, wvb, qkv);
  cvt_f32_bf16_k<<<dim3(2048), dim3(256), 0, stream>>>(wo, wob, 16777216 / 8);
  norm_rope<<<dim3(40960), dim3(256), 0, stream>>>(qkv, qnw, knw, qr, kr);
  transpose_v<<<dim3(32, 16), dim3(256), 0, stream>>>(qkv, vt);
  attn_fwd<<<dim3(16, 64), dim3(256), 0, stream>>>(qr, kr, vt, ao);

  gemm256<1, float><<<dim3(256), dim3(512), 0, stream>>>(ao, wob, nullptr, nullptr, out);
}